// Round 1
// baseline (1172.865 us; speedup 1.0000x reference)
//
#include <hip/hip_runtime.h>
#include <hip/hip_bf16.h>
#include <stdint.h>

typedef __attribute__((__ext_vector_type__(8))) __bf16 bf16x8;
typedef __attribute__((__ext_vector_type__(4))) __bf16 bf16x4;
typedef __attribute__((__ext_vector_type__(4))) float  f32x4;

// async 16B global->LDS (dest = wave-uniform base + lane*16)
__device__ __forceinline__ void gl_lds16(const void* g, void* l) {
  __builtin_amdgcn_global_load_lds(
      (__attribute__((address_space(1))) void*)(uintptr_t)g,
      (__attribute__((address_space(3))) void*)(unsigned)(uintptr_t)l,
      16, 0, 0);
}

// ---------------- instance-norm stats: mean + rstd per (b,c) ----------------
__global__ void k_stats(const float* __restrict__ x, float* __restrict__ stats) {
  int bc = blockIdx.x;                              // 0..2047
  const float4* p = (const float4*)(x + (size_t)bc * 4096);
  float s = 0.f, ss = 0.f;
  for (int i = threadIdx.x; i < 1024; i += 256) {
    float4 v = p[i];
    s  += v.x + v.y + v.z + v.w;
    ss += v.x*v.x + v.y*v.y + v.z*v.z + v.w*v.w;
  }
  #pragma unroll
  for (int o = 32; o > 0; o >>= 1) { s += __shfl_down(s, o); ss += __shfl_down(ss, o); }
  __shared__ float sh[8];
  int wv = threadIdx.x >> 6;
  if ((threadIdx.x & 63) == 0) { sh[wv] = s; sh[4 + wv] = ss; }
  __syncthreads();
  if (threadIdx.x == 0) {
    float S = sh[0]+sh[1]+sh[2]+sh[3], SS = sh[4]+sh[5]+sh[6]+sh[7];
    float m = S * (1.f/4096.f);
    float var = SS * (1.f/4096.f) - m*m;
    stats[bc] = m;
    stats[2048 + bc] = rsqrtf(var + 1e-5f);
  }
}

// ---------------- labels: last j with segmap>0 (one-hot -> the label) -------
__global__ void k_labels(const float* __restrict__ segmap, int* __restrict__ labels) {
  int idx = blockIdx.x*256 + threadIdx.x;           // 0..32767
  int b = idx >> 12, pix = idx & 4095;
  const float* p = segmap + (size_t)b*19*4096 + pix;
  int lab = -1;
  for (int j = 0; j < 19; ++j) if (p[(size_t)j*4096] > 0.f) lab = j;
  labels[idx] = lab;
}

// ---------------- mu[b,j,e] = relu(sum_d sc[b,j,d]*fc_w[j,e,d] + fc_b) ------
__global__ __launch_bounds__(512) void k_mu(const float* __restrict__ sc,
                                            const float* __restrict__ fcw,
                                            const float* __restrict__ fcb,
                                            float* __restrict__ mu) {
  int b = blockIdx.x / 19, j = blockIdx.x % 19;
  __shared__ float s[512];
  s[threadIdx.x] = sc[(b*19 + j)*512 + threadIdx.x];
  __syncthreads();
  int e = threadIdx.x;
  const float4* w4 = (const float4*)(fcw + ((size_t)(j*512 + e))*512);
  const float4* s4 = (const float4*)s;
  float acc = 0.f;
  for (int d = 0; d < 128; ++d) {
    float4 w = w4[d], v = s4[d];
    acc += w.x*v.x + w.y*v.y + w.z*v.z + w.w*v.w;
  }
  acc += fcb[j*512 + e];
  mu[(b*19 + j)*512 + e] = fmaxf(acc, 0.f);
}

// ------------- pack avg conv weights: wpa[k5][c][n512] fp32 -----------------
__global__ void k_pack_avg(const float* __restrict__ g, const float* __restrict__ bt,
                           float* __restrict__ out) {
  int idx = blockIdx.x*256 + threadIdx.x;           // < 25*512*512
  int n = idx & 511, c = (idx >> 9) & 511, k5 = idx >> 18;
  float v = (n < 256) ? g[((size_t)n*512 + c)*25 + k5]
                      : bt[((size_t)(n-256)*512 + c)*25 + k5];
  out[idx] = v;
}

// ------------- pack spade conv weights: wps[k5][n512][c512] bf16 ------------
__global__ void k_pack_spade(const float* __restrict__ g, const float* __restrict__ bt,
                             __bf16* __restrict__ out) {
  int idx = blockIdx.x*256 + threadIdx.x;           // < 25*512*512
  int c = idx & 511, n = (idx >> 9) & 511, k5 = idx >> 18;
  float v = (n < 256) ? g[((size_t)n*512 + c)*25 + k5]
                      : bt[((size_t)(n-256)*512 + c)*25 + k5];
  out[idx] = (__bf16)v;
}

// ------------- pack shared conv weights: wsp[j][k5][o512] fp32 --------------
__global__ void k_pack_wsp(const float* __restrict__ ssw, float* __restrict__ out) {
  int idx = blockIdx.x*256 + threadIdx.x;           // < 19*25*512 = 243200
  if (idx >= 243200) return;
  int o = idx & 511, k5 = (idx >> 9) % 25, j = idx / 12800;
  out[idx] = ssw[((size_t)o*19 + j)*25 + k5];
}

// ------------- A[b,j,k5,n] = sum_c mu[b,j,c] * wpa[k5][c][n] ----------------
__global__ __launch_bounds__(512) void k_A_avg(const float* __restrict__ mu,
                                               const float* __restrict__ wpa,
                                               float* __restrict__ A) {
  int b = blockIdx.x / 25, k5 = blockIdx.x % 25;
  __shared__ float mus[19*512];
  for (int i = threadIdx.x; i < 19*512; i += 512) mus[i] = mu[b*19*512 + i];
  __syncthreads();
  int n = threadIdx.x;
  float acc[19];
  #pragma unroll
  for (int j = 0; j < 19; ++j) acc[j] = 0.f;
  const float* wp = wpa + (size_t)k5*262144 + n;
  const float4* mus4 = (const float4*)mus;
  for (int c4 = 0; c4 < 128; ++c4) {
    float w0 = wp[(c4*4+0)*512];
    float w1 = wp[(c4*4+1)*512];
    float w2 = wp[(c4*4+2)*512];
    float w3 = wp[(c4*4+3)*512];
    #pragma unroll
    for (int j = 0; j < 19; ++j) {
      float4 m4 = mus4[j*128 + c4];
      acc[j] += m4.x*w0 + m4.y*w1 + m4.z*w2 + m4.w*w3;
    }
  }
  #pragma unroll
  for (int j = 0; j < 19; ++j)
    A[((size_t)((b*19 + j)*25 + k5))*512 + n] = acc[j];
}

// ------------- actv (padded NHWC bf16): one-hot conv == weight gather -------
__global__ void k_actv(const int* __restrict__ labels, const float* __restrict__ wsp,
                       const float* __restrict__ ssb, __bf16* __restrict__ actv) {
  int b = blockIdx.x >> 6, h = blockIdx.x & 63;
  __shared__ int lab[5*68];
  for (int i = threadIdx.x; i < 5*68; i += 256) {
    int dh = i / 68, xx = i % 68;
    int hh = h + dh - 2, ww = xx - 2;
    lab[i] = (hh >= 0 && hh < 64 && ww >= 0 && ww < 64) ? labels[b*4096 + hh*64 + ww] : -1;
  }
  __syncthreads();
  int o0 = threadIdx.x, o1 = threadIdx.x + 256;
  float bb0 = ssb[o0], bb1 = ssb[o1];
  for (int w = 0; w < 64; ++w) {
    float a0 = bb0, a1 = bb1;
    #pragma unroll
    for (int dh = 0; dh < 5; ++dh) {
      #pragma unroll
      for (int dw = 0; dw < 5; ++dw) {
        int l = lab[dh*68 + w + dw];          // wave-uniform
        if (l >= 0) {
          const float* p = wsp + (l*25 + dh*5 + dw)*512;
          a0 += p[o0]; a1 += p[o1];
        }
      }
    }
    size_t bse = (((size_t)b*68 + h + 2)*68 + (w + 2)) * 512;
    actv[bse + o0] = (__bf16)fmaxf(a0, 0.f);
    actv[bse + o1] = (__bf16)fmaxf(a1, 0.f);
  }
}

// ------------- big implicit-GEMM conv: M=32768, N=512, K=12800, bf16 MFMA ---
// A = padded-NHWC actv, B = wps[k5][n][c]; LDS tiles 128x64 with XOR chunk
// swizzle (phys16Bchunk = logchunk ^ (row&7)) so frag b128 reads hit all 32 banks.
__global__ __launch_bounds__(256) void k_conv(
    const __bf16* __restrict__ actv, const __bf16* __restrict__ wpk,
    const float* __restrict__ sgb, const float* __restrict__ sbb,
    __bf16* __restrict__ gbs) {
  __shared__ __align__(16) __bf16 ldsA[128*64];
  __shared__ __align__(16) __bf16 ldsB[128*64];
  const int tid = threadIdx.x;
  const int wv = tid >> 6, lane = tid & 63;
  const int m0 = blockIdx.x * 128, n0 = blockIdx.y * 128;
  const int b = m0 >> 12;

  int aoff[4], boff[4];
  #pragma unroll
  for (int i = 0; i < 4; ++i) {
    int p = (wv*4 + i)*64 + lane;     // 16B slot in tile
    int r = p >> 3, pc = p & 7;
    int cl = pc ^ (r & 7);            // logical chunk this lane fetches
    int pix = (m0 + r) & 4095;
    int h = pix >> 6, w = pix & 63;
    aoff[i] = ((b*68 + h)*68 + w)*512 + cl*8;
    boff[i] = (n0 + r)*512 + cl*8;
  }

  f32x4 acc[4][4] = {};
  const int wm = (wv >> 1) * 64, wn = (wv & 1) * 64;
  const int l15 = lane & 15, q = lane >> 4;

  for (int k5 = 0; k5 < 25; ++k5) {
    const int kh = k5 / 5, kw = k5 % 5;
    const int a_k = (kh*68 + kw)*512;
    const int b_k = k5 * 262144;
    for (int kc = 0; kc < 8; ++kc) {
      #pragma unroll
      for (int i = 0; i < 4; ++i) {
        gl_lds16(actv + aoff[i] + a_k + kc*64, ldsA + (wv*4 + i)*512);
        gl_lds16(wpk  + boff[i] + b_k + kc*64, ldsB + (wv*4 + i)*512);
      }
      __syncthreads();
      #pragma unroll
      for (int s = 0; s < 2; ++s) {
        bf16x8 af[4], bfr[4];
        #pragma unroll
        for (int mi = 0; mi < 4; ++mi) {
          int row = wm + mi*16 + l15;
          int ch = (s*4 + q) ^ (row & 7);
          af[mi] = *(const bf16x8*)(ldsA + row*64 + ch*8);
        }
        #pragma unroll
        for (int ni = 0; ni < 4; ++ni) {
          int row = wn + ni*16 + l15;
          int ch = (s*4 + q) ^ (row & 7);
          bfr[ni] = *(const bf16x8*)(ldsB + row*64 + ch*8);
        }
        #pragma unroll
        for (int mi = 0; mi < 4; ++mi)
          #pragma unroll
          for (int ni = 0; ni < 4; ++ni)
            acc[mi][ni] = __builtin_amdgcn_mfma_f32_16x16x32_bf16(
                af[mi], bfr[ni], acc[mi][ni], 0, 0, 0);
      }
      __syncthreads();
    }
  }

  // epilogue: D[row=q*4+r][col=l15]; store to gbs[b][n][pix] (+spade bias)
  #pragma unroll
  for (int ni = 0; ni < 4; ++ni) {
    int n = n0 + wn + ni*16 + l15;
    float bias = (n < 256) ? sgb[n] : sbb[n - 256];
    #pragma unroll
    for (int mi = 0; mi < 4; ++mi) {
      int pix = (m0 + wm + mi*16 + q*4) & 4095;
      size_t base = ((size_t)(b*512 + n))*4096 + pix;
      #pragma unroll
      for (int r = 0; r < 4; ++r)
        gbs[base + r] = (__bf16)(acc[mi][ni][r] + bias);
    }
  }
}

// ------------- avg path: 25-term gather of A rows per pixel -----------------
__global__ void k_gather(const int* __restrict__ labels, const float* __restrict__ A,
                         const float* __restrict__ cgb, const float* __restrict__ cbb,
                         __bf16* __restrict__ gba) {
  int m = blockIdx.x;
  int b = m >> 12, pix = m & 4095;
  int h = pix >> 6, w = pix & 63;
  __shared__ int base[25];
  if (threadIdx.x < 25) {
    int dh = threadIdx.x / 5, dw = threadIdx.x % 5;
    int hh = h + dh - 2, ww = w + dw - 2;
    int l = (hh >= 0 && hh < 64 && ww >= 0 && ww < 64) ? labels[b*4096 + hh*64 + ww] : -1;
    base[threadIdx.x] = (l >= 0) ? ((b*19 + l)*25 + threadIdx.x)*512 : -1;
  }
  __syncthreads();
  int n = threadIdx.x;                     // 0..255
  float a0 = cgb[n], a1 = cbb[n];
  #pragma unroll
  for (int k = 0; k < 25; ++k) {
    int bs = base[k];                      // wave-uniform
    if (bs >= 0) { a0 += A[bs + n]; a1 += A[bs + n + 256]; }
  }
  size_t o = ((size_t)b*512)*4096 + pix;
  gba[o + (size_t)n*4096]        = (__bf16)a0;
  gba[o + (size_t)(n+256)*4096]  = (__bf16)a1;
}

// ------------- final blend: normalized*(1+gf)+bf ----------------------------
__global__ void k_final(const float* __restrict__ x, const float* __restrict__ stats,
                        const __bf16* __restrict__ gba, const __bf16* __restrict__ gbs,
                        const float* __restrict__ blg, const float* __restrict__ blb,
                        float* __restrict__ out) {
  int idx = blockIdx.x*256 + threadIdx.x;
  int e = idx << 2;
  int bc = e >> 12;
  int b = bc >> 8, o = bc & 255;
  float mean = stats[bc], rstd = stats[2048 + bc];
  float ga = 1.f / (1.f + expf(-blg[0]));
  float ba = 1.f / (1.f + expf(-blb[0]));
  float4 xv = *(const float4*)(x + e);
  size_t gi = ((size_t)(b*512 + o))*4096 + (e & 4095);
  bf16x4 g_av = *(const bf16x4*)(gba + gi);
  bf16x4 b_av = *(const bf16x4*)(gba + gi + 1048576);
  bf16x4 g_sp = *(const bf16x4*)(gbs + gi);
  bf16x4 b_sp = *(const bf16x4*)(gbs + gi + 1048576);
  float xs[4] = {xv.x, xv.y, xv.z, xv.w};
  float rs[4];
  #pragma unroll
  for (int i = 0; i < 4; ++i) {
    float gf = ga * (float)g_av[i] + (1.f - ga) * (float)g_sp[i];
    float bf_ = ba * (float)b_av[i] + (1.f - ba) * (float)b_sp[i];
    rs[i] = (xs[i] - mean) * rstd * (1.f + gf) + bf_;
  }
  float4 r; r.x = rs[0]; r.y = rs[1]; r.z = rs[2]; r.w = rs[3];
  *(float4*)(out + e) = r;
}

extern "C" void kernel_launch(void* const* d_in, const int* in_sizes, int n_in,
                              void* d_out, int out_size, void* d_ws, size_t ws_size,
                              hipStream_t stream) {
  const float* x    = (const float*)d_in[0];
  const float* seg  = (const float*)d_in[1];
  const float* sc   = (const float*)d_in[2];
  const float* fcw  = (const float*)d_in[3];
  const float* fcb  = (const float*)d_in[4];
  const float* cgw  = (const float*)d_in[5];
  const float* cgb  = (const float*)d_in[6];
  const float* cbw  = (const float*)d_in[7];
  const float* cbb  = (const float*)d_in[8];
  const float* ssw  = (const float*)d_in[9];
  const float* ssb  = (const float*)d_in[10];
  const float* sgw  = (const float*)d_in[11];
  const float* sgb  = (const float*)d_in[12];
  const float* sbw  = (const float*)d_in[13];
  const float* sbb  = (const float*)d_in[14];
  const float* blg  = (const float*)d_in[15];
  const float* blb  = (const float*)d_in[16];
  float* out = (float*)d_out;

  char* ws = (char*)d_ws;
  size_t off = 0;
  auto alloc = [&](size_t bytes) {
    void* p = ws + off; off += (bytes + 255) & ~(size_t)255; return p;
  };
  float*  stats = (float*)alloc(2048ull*2*4);
  int*    labels= (int*)  alloc(32768ull*4);
  float*  mu    = (float*)alloc(77824ull*4);
  float*  Aav   = (float*)alloc(8ull*19*25*512*4);      // 7.78 MB
  float*  wsp   = (float*)alloc(19ull*25*512*4);        // 0.97 MB
  float*  wpa   = (float*)alloc(25ull*512*512*4);       // 26.2 MB
  __bf16* wps   = (__bf16*)alloc(25ull*512*512*2);      // 13.1 MB
  __bf16* actv  = (__bf16*)alloc(8ull*68*68*512*2);     // 37.9 MB
  __bf16* gba   = (__bf16*)alloc(8ull*512*4096*2);      // 33.5 MB
  __bf16* gbs   = (__bf16*)alloc(8ull*512*4096*2);      // 33.5 MB

  hipMemsetAsync(actv, 0, 8ull*68*68*512*2, stream);    // zero pad border
  k_stats     <<<2048, 256, 0, stream>>>(x, stats);
  k_labels    <<<128, 256, 0, stream>>>(seg, labels);
  k_mu        <<<152, 512, 0, stream>>>(sc, fcw, fcb, mu);
  k_pack_avg  <<<25600, 256, 0, stream>>>(cgw, cbw, wpa);
  k_pack_spade<<<25600, 256, 0, stream>>>(sgw, sbw, wps);
  k_pack_wsp  <<<950, 256, 0, stream>>>(ssw, wsp);
  k_A_avg     <<<200, 512, 0, stream>>>(mu, wpa, Aav);
  k_actv      <<<512, 256, 0, stream>>>(labels, wsp, ssb, actv);
  k_conv      <<<dim3(256, 4), 256, 0, stream>>>(actv, wps, sgb, sbb, gbs);
  k_gather    <<<32768, 256, 0, stream>>>(labels, Aav, cgb, cbb, gba);
  k_final     <<<8192, 256, 0, stream>>>(x, stats, gba, gbs, blg, blb, out);
}

// Round 2
// 1118.913 us; speedup vs baseline: 1.0482x; 1.0482x over previous
//
#include <hip/hip_runtime.h>
#include <hip/hip_bf16.h>
#include <stdint.h>

typedef __attribute__((__ext_vector_type__(8))) __bf16 bf16x8;
typedef __attribute__((__ext_vector_type__(4))) __bf16 bf16x4;
typedef __attribute__((__ext_vector_type__(4))) float  f32x4;

// async 16B global->LDS (dest = wave-uniform base + lane*16)
__device__ __forceinline__ void gl_lds16(const void* g, void* l) {
  __builtin_amdgcn_global_load_lds(
      (__attribute__((address_space(1))) void*)(uintptr_t)g,
      (__attribute__((address_space(3))) void*)(unsigned)(uintptr_t)l,
      16, 0, 0);
}

// ---------------- instance-norm stats: mean + rstd per (b,c) ----------------
__global__ void k_stats(const float* __restrict__ x, float* __restrict__ stats) {
  int bc = blockIdx.x;                              // 0..2047
  const float4* p = (const float4*)(x + (size_t)bc * 4096);
  float s = 0.f, ss = 0.f;
  for (int i = threadIdx.x; i < 1024; i += 256) {
    float4 v = p[i];
    s  += v.x + v.y + v.z + v.w;
    ss += v.x*v.x + v.y*v.y + v.z*v.z + v.w*v.w;
  }
  #pragma unroll
  for (int o = 32; o > 0; o >>= 1) { s += __shfl_down(s, o); ss += __shfl_down(ss, o); }
  __shared__ float sh[8];
  int wv = threadIdx.x >> 6;
  if ((threadIdx.x & 63) == 0) { sh[wv] = s; sh[4 + wv] = ss; }
  __syncthreads();
  if (threadIdx.x == 0) {
    float S = sh[0]+sh[1]+sh[2]+sh[3], SS = sh[4]+sh[5]+sh[6]+sh[7];
    float m = S * (1.f/4096.f);
    float var = SS * (1.f/4096.f) - m*m;
    stats[bc] = m;
    stats[2048 + bc] = rsqrtf(var + 1e-5f);
  }
}

// ---------------- labels: last j with segmap>0 ------------------------------
__global__ void k_labels(const float* __restrict__ segmap, int* __restrict__ labels) {
  int idx = blockIdx.x*256 + threadIdx.x;           // 0..32767
  int b = idx >> 12, pix = idx & 4095;
  const float* p = segmap + (size_t)b*19*4096 + pix;
  int lab = -1;
  for (int j = 0; j < 19; ++j) if (p[(size_t)j*4096] > 0.f) lab = j;
  labels[idx] = lab;
}

// ---------------- mu[b,j,e] = relu(sum_d sc[b,j,d]*fc_w[j,e,d] + fc_b) ------
__global__ __launch_bounds__(512) void k_mu(const float* __restrict__ sc,
                                            const float* __restrict__ fcw,
                                            const float* __restrict__ fcb,
                                            float* __restrict__ mu) {
  int b = blockIdx.x / 19, j = blockIdx.x % 19;
  __shared__ float s[512];
  s[threadIdx.x] = sc[(b*19 + j)*512 + threadIdx.x];
  __syncthreads();
  int e = threadIdx.x;
  const float4* w4 = (const float4*)(fcw + ((size_t)(j*512 + e))*512);
  const float4* s4 = (const float4*)s;
  float acc = 0.f;
  for (int d = 0; d < 128; ++d) {
    float4 w = w4[d], v = s4[d];
    acc += w.x*v.x + w.y*v.y + w.z*v.z + w.w*v.w;
  }
  acc += fcb[j*512 + e];
  mu[(b*19 + j)*512 + e] = fmaxf(acc, 0.f);
}

// ---- pack avg conv weights, coalesced tile transpose: wpa[k5][c][n] fp32 ---
// src [n][c][k5] (g=gamma n<256, bt=beta). Tile: 16 n x 16 c x 25 k5.
__global__ void k_pack_avg(const float* __restrict__ g, const float* __restrict__ bt,
                           float* __restrict__ out) {
  __shared__ float s[16*401];
  int n0 = (blockIdx.x & 31) * 16, c0 = (blockIdx.x >> 5) * 16;
  for (int i = threadIdx.x; i < 6400; i += 256) {
    int nn = i / 400, qq = i % 400;
    int n = n0 + nn;
    const float* src = (n < 256) ? g + (size_t)n*12800 : bt + (size_t)(n-256)*12800;
    s[nn*401 + qq] = src[c0*25 + qq];
  }
  __syncthreads();
  for (int i = threadIdx.x; i < 6400; i += 256) {
    int nn = i & 15, rest = i >> 4;
    int k5 = rest % 25, cc = rest / 25;
    out[((size_t)k5*512 + c0 + cc)*512 + n0 + nn] = s[nn*401 + cc*25 + k5];
  }
}

// ---- pack spade conv weights, coalesced: wps[k5][n][c] bf16 ----------------
__global__ void k_pack_spade(const float* __restrict__ g, const float* __restrict__ bt,
                             __bf16* __restrict__ out) {
  int n = blockIdx.x;                               // 0..511
  const float* src = (n < 256) ? g + (size_t)n*12800 : bt + (size_t)(n-256)*12800;
  __shared__ float s[12800];
  for (int i = threadIdx.x; i < 12800; i += 256) s[i] = src[i];
  __syncthreads();
  for (int k5 = 0; k5 < 25; ++k5)
    for (int c = threadIdx.x; c < 512; c += 256)
      out[((size_t)k5*512 + n)*512 + c] = (__bf16)s[c*25 + k5];
}

// ---- pack shared conv weights: wspb[j][k5][o512] bf16 ----------------------
__global__ void k_pack_wsp(const float* __restrict__ ssw, __bf16* __restrict__ out) {
  int idx = blockIdx.x*256 + threadIdx.x;           // < 243200
  if (idx >= 243200) return;
  int o = idx & 511, k5 = (idx >> 9) % 25, j = idx / 12800;
  out[idx] = (__bf16)ssw[((size_t)o*19 + j)*25 + k5];
}

// ---- A[b,j,k5,n] = sum_c mu[b,j,c]*wpa[k5][c][n]  (mu via scalar loads) ----
__global__ __launch_bounds__(512) void k_A_avg(const float* __restrict__ mu,
                                               const float* __restrict__ wpa,
                                               __bf16* __restrict__ A) {
  int b = blockIdx.x / 25, k5 = blockIdx.x % 25;
  int n = threadIdx.x;
  const float* wp = wpa + (size_t)k5*262144 + n;
  const float* mub = mu + b*19*512;                 // wave-uniform rows -> s_load
  float acc[19];
  #pragma unroll
  for (int j = 0; j < 19; ++j) acc[j] = 0.f;
  for (int c = 0; c < 512; ++c) {
    float w = wp[(size_t)c*512];
    #pragma unroll
    for (int j = 0; j < 19; ++j) acc[j] += mub[j*512 + c] * w;
  }
  #pragma unroll
  for (int j = 0; j < 19; ++j)
    A[((size_t)((b*19 + j)*25 + k5))*512 + n] = (__bf16)acc[j];
}

// ---- actv (padded NHWC bf16): one-hot conv == weight-row gather ------------
__global__ void k_actv(const int* __restrict__ labels, const __bf16* __restrict__ wsp,
                       const float* __restrict__ ssb, __bf16* __restrict__ actv) {
  int b = blockIdx.x >> 6, h = blockIdx.x & 63;
  __shared__ int lab[5*68];
  for (int i = threadIdx.x; i < 5*68; i += 256) {
    int dh = i / 68, xx = i % 68;
    int hh = h + dh - 2, ww = xx - 2;
    lab[i] = (hh >= 0 && hh < 64 && ww >= 0 && ww < 64) ? labels[b*4096 + hh*64 + ww] : -1;
  }
  __syncthreads();
  int o0 = threadIdx.x, o1 = threadIdx.x + 256;
  float bb0 = ssb[o0], bb1 = ssb[o1];
  for (int w = 0; w < 64; ++w) {
    float a0 = bb0, a1 = bb1;
    #pragma unroll
    for (int dh = 0; dh < 5; ++dh) {
      #pragma unroll
      for (int dw = 0; dw < 5; ++dw) {
        int l = lab[dh*68 + w + dw];          // wave-uniform
        if (l >= 0) {
          const __bf16* p = wsp + (l*25 + dh*5 + dw)*512;
          a0 += (float)p[o0]; a1 += (float)p[o1];
        }
      }
    }
    size_t bse = (((size_t)b*68 + h + 2)*68 + (w + 2)) * 512;
    actv[bse + o0] = (__bf16)fmaxf(a0, 0.f);
    actv[bse + o1] = (__bf16)fmaxf(a1, 0.f);
  }
}

// ---- big implicit-GEMM conv: M=32768, N=512, K=12800, bf16 MFMA ------------
// Block tile 256x128. 4 waves own disjoint 64-row m-strips; A-fragments read
// directly global->VGPR (no barriers on A path, 16 fully-used 64B lines per
// load). B k5-slice staged in halves (64KB, XOR chunk swizzle) into LDS and
// broadcast to all waves. 256 MFMA between barrier pairs.
__global__ __launch_bounds__(256, 2) void k_conv(
    const __bf16* __restrict__ actv, const __bf16* __restrict__ wps,
    const float* __restrict__ sgb, const float* __restrict__ sbb,
    __bf16* __restrict__ gbs) {
  __shared__ __align__(16) __bf16 ldsB[32768];      // 64 KB: [n 128][c 256]
  const int tid = threadIdx.x, wv = tid >> 6, lane = tid & 63;
  const int l15 = lane & 15, q = lane >> 4;
  const int m0 = blockIdx.x * 256, n0 = blockIdx.y * 128;
  const int b = m0 >> 12;

  const __bf16* ap[4];
  #pragma unroll
  for (int mi = 0; mi < 4; ++mi) {
    int pix = (m0 + wv*64 + mi*16 + l15) & 4095;
    int h = pix >> 6, w = pix & 63;
    ap[mi] = actv + ((size_t)((b*68 + h)*68 + w))*512 + q*8;
  }

  f32x4 acc[4][8] = {};
  const int nb = wv*2 + (lane >> 5), pc = lane & 31;

  for (int k5 = 0; k5 < 25; ++k5) {
    const int aoff = ((k5/5)*68 + (k5%5)) * 512;
    const size_t bbase = ((size_t)k5*512 + n0) * 512;
    for (int hf = 0; hf < 2; ++hf) {
      __syncthreads();
      #pragma unroll
      for (int i = 0; i < 16; ++i) {
        int n = i*8 + nb;
        int lc = pc ^ (n & 31);
        gl_lds16(wps + bbase + (size_t)n*512 + hf*256 + lc*8,
                 ldsB + (i*256 + wv*64)*8);
      }
      __syncthreads();
      const int khf = hf*256;
      #pragma unroll 2
      for (int ks = 0; ks < 8; ++ks) {
        bf16x8 af[4];
        #pragma unroll
        for (int mi = 0; mi < 4; ++mi)
          af[mi] = *(const bf16x8*)(ap[mi] + aoff + khf + ks*32);
        #pragma unroll
        for (int ni = 0; ni < 8; ++ni) {
          int row = ni*16 + l15;
          int phys = (ks*4 + q) ^ (row & 31);
          bf16x8 bfr = *(const bf16x8*)(ldsB + row*256 + phys*8);
          #pragma unroll
          for (int mi = 0; mi < 4; ++mi)
            acc[mi][ni] = __builtin_amdgcn_mfma_f32_16x16x32_bf16(
                af[mi], bfr, acc[mi][ni], 0, 0, 0);
        }
      }
    }
  }

  // epilogue: D[row=q*4+r][col=l15]; NHWC store gbs[m][n] (+spade bias)
  #pragma unroll
  for (int ni = 0; ni < 8; ++ni) {
    int n = n0 + ni*16 + l15;
    float bias = (n < 256) ? sgb[n] : sbb[n - 256];
    #pragma unroll
    for (int mi = 0; mi < 4; ++mi) {
      int m = m0 + wv*64 + mi*16 + q*4;
      size_t base = (size_t)m*512 + n;
      #pragma unroll
      for (int r = 0; r < 4; ++r)
        gbs[base + (size_t)r*512] = (__bf16)(acc[mi][ni][r] + bias);
    }
  }
}

// ---- avg path: 25-term gather of A rows per pixel, NHWC coalesced out ------
__global__ void k_gather(const int* __restrict__ labels, const __bf16* __restrict__ A,
                         const float* __restrict__ cgb, const float* __restrict__ cbb,
                         __bf16* __restrict__ gba) {
  int m = blockIdx.x;
  int b = m >> 12, pix = m & 4095;
  int h = pix >> 6, w = pix & 63;
  __shared__ int base[25];
  if (threadIdx.x < 25) {
    int dh = threadIdx.x / 5, dw = threadIdx.x % 5;
    int hh = h + dh - 2, ww = w + dw - 2;
    int l = (hh >= 0 && hh < 64 && ww >= 0 && ww < 64) ? labels[b*4096 + hh*64 + ww] : -1;
    base[threadIdx.x] = (l >= 0) ? ((b*19 + l)*25 + threadIdx.x)*512 : -1;
  }
  __syncthreads();
  int n = threadIdx.x;                     // 0..255
  float a0 = cgb[n], a1 = cbb[n];
  #pragma unroll
  for (int k = 0; k < 25; ++k) {
    int bs = base[k];                      // wave-uniform rows
    if (bs >= 0) { a0 += (float)A[bs + n]; a1 += (float)A[bs + n + 256]; }
  }
  size_t o = (size_t)m * 512;
  gba[o + n]       = (__bf16)a0;
  gba[o + 256 + n] = (__bf16)a1;
}

// ---- final blend: NHWC->NCHW via LDS transpose -----------------------------
__global__ __launch_bounds__(256) void k_final(
    const float* __restrict__ x, const float* __restrict__ stats,
    const __bf16* __restrict__ gba, const __bf16* __restrict__ gbs,
    const float* __restrict__ blg, const float* __restrict__ blb,
    float* __restrict__ out) {
  __shared__ __bf16 tg_av[64*66], tb_av[64*66], tg_sp[64*66], tb_sp[64*66];
  int bidx = blockIdx.x;                   // 8b x 4ct x 64pt = 2048
  int pt = bidx & 63, ct = (bidx >> 6) & 3, b = bidx >> 8;
  int c0 = ct*64, p0 = pt*64;
  for (int i = threadIdx.x; i < 4096; i += 256) {
    int p = i >> 6, c = i & 63;
    size_t src = ((size_t)b*4096 + p0 + p)*512;
    int d = p*66 + c;
    tg_av[d] = gba[src + c0 + c];
    tb_av[d] = gba[src + 256 + c0 + c];
    tg_sp[d] = gbs[src + c0 + c];
    tb_sp[d] = gbs[src + 256 + c0 + c];
  }
  __syncthreads();
  float ga = 1.f / (1.f + expf(-blg[0]));
  float ba = 1.f / (1.f + expf(-blb[0]));
  int p = threadIdx.x & 63;
  for (int cl = threadIdx.x >> 6; cl < 64; cl += 4) {
    int c = c0 + cl;
    int bc = b*256 + c;
    float mean = stats[bc], rstd = stats[2048 + bc];
    size_t o = (size_t)bc*4096 + p0 + p;
    int d = p*66 + cl;
    float gf  = ga*(float)tg_av[d] + (1.f - ga)*(float)tg_sp[d];
    float bf_ = ba*(float)tb_av[d] + (1.f - ba)*(float)tb_sp[d];
    out[o] = (x[o] - mean)*rstd*(1.f + gf) + bf_;
  }
}

extern "C" void kernel_launch(void* const* d_in, const int* in_sizes, int n_in,
                              void* d_out, int out_size, void* d_ws, size_t ws_size,
                              hipStream_t stream) {
  const float* x    = (const float*)d_in[0];
  const float* seg  = (const float*)d_in[1];
  const float* sc   = (const float*)d_in[2];
  const float* fcw  = (const float*)d_in[3];
  const float* fcb  = (const float*)d_in[4];
  const float* cgw  = (const float*)d_in[5];
  const float* cgb  = (const float*)d_in[6];
  const float* cbw  = (const float*)d_in[7];
  const float* cbb  = (const float*)d_in[8];
  const float* ssw  = (const float*)d_in[9];
  const float* ssb  = (const float*)d_in[10];
  const float* sgw  = (const float*)d_in[11];
  const float* sgb  = (const float*)d_in[12];
  const float* sbw  = (const float*)d_in[13];
  const float* sbb  = (const float*)d_in[14];
  const float* blg  = (const float*)d_in[15];
  const float* blb  = (const float*)d_in[16];
  float* out = (float*)d_out;

  char* ws = (char*)d_ws;
  size_t off = 0;
  auto alloc = [&](size_t bytes) {
    void* p = ws + off; off += (bytes + 255) & ~(size_t)255; return p;
  };
  float*  stats = (float*)alloc(2048ull*2*4);
  int*    labels= (int*)  alloc(32768ull*4);
  float*  mu    = (float*)alloc(77824ull*4);
  __bf16* Aav   = (__bf16*)alloc(8ull*19*25*512*2);     // 3.9 MB
  __bf16* wspb  = (__bf16*)alloc(19ull*25*512*2);       // 0.49 MB
  float*  wpa   = (float*)alloc(25ull*512*512*4);       // 26.2 MB
  __bf16* wps   = (__bf16*)alloc(25ull*512*512*2);      // 13.1 MB
  __bf16* actv  = (__bf16*)alloc(8ull*68*68*512*2);     // 37.9 MB
  __bf16* gba   = (__bf16*)alloc(8ull*4096*512*2);      // 33.5 MB (NHWC)
  __bf16* gbs   = (__bf16*)alloc(8ull*4096*512*2);      // 33.5 MB (NHWC)

  hipMemsetAsync(actv, 0, 8ull*68*68*512*2, stream);    // zero pad border
  k_stats     <<<2048, 256, 0, stream>>>(x, stats);
  k_labels    <<<128, 256, 0, stream>>>(seg, labels);
  k_mu        <<<152, 512, 0, stream>>>(sc, fcw, fcb, mu);
  k_pack_avg  <<<1024, 256, 0, stream>>>(cgw, cbw, wpa);
  k_pack_spade<<<512, 256, 0, stream>>>(sgw, sbw, wps);
  k_pack_wsp  <<<950, 256, 0, stream>>>(ssw, wspb);
  k_A_avg     <<<200, 512, 0, stream>>>(mu, wpa, Aav);
  k_actv      <<<512, 256, 0, stream>>>(labels, wspb, ssb, actv);
  k_conv      <<<dim3(128, 4), 256, 0, stream>>>(actv, wps, sgb, sbb, gbs);
  k_gather    <<<32768, 256, 0, stream>>>(labels, Aav, cgb, cbb, gba);
  k_final     <<<2048, 256, 0, stream>>>(x, stats, gba, gbs, blg, blb, out);
}

// Round 3
// 901.056 us; speedup vs baseline: 1.3017x; 1.2418x over previous
//
#include <hip/hip_runtime.h>
#include <hip/hip_bf16.h>
#include <stdint.h>

typedef __attribute__((__ext_vector_type__(8))) __bf16 bf16x8;
typedef __attribute__((__ext_vector_type__(4))) __bf16 bf16x4;
typedef __attribute__((__ext_vector_type__(2))) __bf16 bf16x2;
typedef __attribute__((__ext_vector_type__(4))) float  f32x4;

// async 16B global->LDS (dest = wave-uniform base + lane*16)
__device__ __forceinline__ void gl_lds16(const void* g, void* l) {
  __builtin_amdgcn_global_load_lds(
      (__attribute__((address_space(1))) void*)(uintptr_t)g,
      (__attribute__((address_space(3))) void*)(unsigned)(uintptr_t)l,
      16, 0, 0);
}

// ---------------- instance-norm stats: mean + rstd per (b,c) ----------------
__global__ void k_stats(const float* __restrict__ x, float* __restrict__ stats) {
  int bc = blockIdx.x;                              // 0..2047
  const float4* p = (const float4*)(x + (size_t)bc * 4096);
  float s = 0.f, ss = 0.f;
  for (int i = threadIdx.x; i < 1024; i += 256) {
    float4 v = p[i];
    s  += v.x + v.y + v.z + v.w;
    ss += v.x*v.x + v.y*v.y + v.z*v.z + v.w*v.w;
  }
  #pragma unroll
  for (int o = 32; o > 0; o >>= 1) { s += __shfl_down(s, o); ss += __shfl_down(ss, o); }
  __shared__ float sh[8];
  int wv = threadIdx.x >> 6;
  if ((threadIdx.x & 63) == 0) { sh[wv] = s; sh[4 + wv] = ss; }
  __syncthreads();
  if (threadIdx.x == 0) {
    float S = sh[0]+sh[1]+sh[2]+sh[3], SS = sh[4]+sh[5]+sh[6]+sh[7];
    float m = S * (1.f/4096.f);
    float var = SS * (1.f/4096.f) - m*m;
    stats[bc] = m;
    stats[2048 + bc] = rsqrtf(var + 1e-5f);
  }
}

// ---------------- labels: last j with segmap>0 ------------------------------
__global__ void k_labels(const float* __restrict__ segmap, int* __restrict__ labels) {
  int idx = blockIdx.x*256 + threadIdx.x;           // 0..32767
  int b = idx >> 12, pix = idx & 4095;
  const float* p = segmap + (size_t)b*19*4096 + pix;
  int lab = -1;
  for (int j = 0; j < 19; ++j) if (p[(size_t)j*4096] > 0.f) lab = j;
  labels[idx] = lab;
}

// ---------------- mu[b,j,e] = relu(sum_d sc[b,j,d]*fc_w[j,e,d] + fc_b) ------
__global__ __launch_bounds__(512) void k_mu(const float* __restrict__ sc,
                                            const float* __restrict__ fcw,
                                            const float* __restrict__ fcb,
                                            float* __restrict__ mu) {
  int b = blockIdx.x / 19, j = blockIdx.x % 19;
  __shared__ float s[512];
  s[threadIdx.x] = sc[(b*19 + j)*512 + threadIdx.x];
  __syncthreads();
  int e = threadIdx.x;
  const float4* w4 = (const float4*)(fcw + ((size_t)(j*512 + e))*512);
  const float4* s4 = (const float4*)s;
  float acc = 0.f;
  for (int d = 0; d < 128; ++d) {
    float4 w = w4[d], v = s4[d];
    acc += w.x*v.x + w.y*v.y + w.z*v.z + w.w*v.w;
  }
  acc += fcb[j*512 + e];
  mu[(b*19 + j)*512 + e] = fmaxf(acc, 0.f);
}

// ---- pack avg conv weights, coalesced tile transpose: wpa[k5][c][n] fp32 ---
__global__ void k_pack_avg(const float* __restrict__ g, const float* __restrict__ bt,
                           float* __restrict__ out) {
  __shared__ float s[16*401];
  int n0 = (blockIdx.x & 31) * 16, c0 = (blockIdx.x >> 5) * 16;
  for (int i = threadIdx.x; i < 6400; i += 256) {
    int nn = i / 400, qq = i % 400;
    int n = n0 + nn;
    const float* src = (n < 256) ? g + (size_t)n*12800 : bt + (size_t)(n-256)*12800;
    s[nn*401 + qq] = src[c0*25 + qq];
  }
  __syncthreads();
  for (int i = threadIdx.x; i < 6400; i += 256) {
    int nn = i & 15, rest = i >> 4;
    int k5 = rest % 25, cc = rest / 25;
    out[((size_t)k5*512 + c0 + cc)*512 + n0 + nn] = s[nn*401 + cc*25 + k5];
  }
}

// ---- pack spade conv weights, coalesced: wps[k5][n][c] bf16 ----------------
__global__ void k_pack_spade(const float* __restrict__ g, const float* __restrict__ bt,
                             __bf16* __restrict__ out) {
  int n = blockIdx.x;                               // 0..511
  const float* src = (n < 256) ? g + (size_t)n*12800 : bt + (size_t)(n-256)*12800;
  __shared__ float s[12800];
  for (int i = threadIdx.x; i < 12800; i += 256) s[i] = src[i];
  __syncthreads();
  for (int k5 = 0; k5 < 25; ++k5)
    for (int c = threadIdx.x; c < 512; c += 256)
      out[((size_t)k5*512 + n)*512 + c] = (__bf16)s[c*25 + k5];
}

// ---- pack shared conv weights: wspb[j][k5][o512] bf16, j=19 = zero row -----
__global__ void k_pack_wsp(const float* __restrict__ ssw, __bf16* __restrict__ out) {
  int idx = blockIdx.x*256 + threadIdx.x;           // < 20*25*512 = 256000
  if (idx >= 256000) return;
  int o = idx & 511, k5 = (idx >> 9) % 25, j = idx / 12800;
  out[idx] = (j < 19) ? (__bf16)ssw[((size_t)o*19 + j)*25 + k5] : (__bf16)0.f;
}

// ---- A[b,j,k5,n] = sum_c mu[b,j,c]*wpa[k5][c][n]  (mu via scalar loads) ----
__global__ __launch_bounds__(512) void k_A_avg(const float* __restrict__ mu,
                                               const float* __restrict__ wpa,
                                               __bf16* __restrict__ A) {
  int b = blockIdx.x / 25, k5 = blockIdx.x % 25;
  int n = threadIdx.x;
  const float* wp = wpa + (size_t)k5*262144 + n;
  const float* mub = mu + b*19*512;                 // wave-uniform rows -> s_load
  float acc[19];
  #pragma unroll
  for (int j = 0; j < 19; ++j) acc[j] = 0.f;
  for (int c = 0; c < 512; ++c) {
    float w = wp[(size_t)c*512];
    #pragma unroll
    for (int j = 0; j < 19; ++j) acc[j] += mub[j*512 + c] * w;
  }
  #pragma unroll
  for (int j = 0; j < 19; ++j)
    A[((size_t)((b*19 + j)*25 + k5))*512 + n] = (__bf16)acc[j];
}

// ---- actv (padded NHWC bf16): debranched weight-row gather -----------------
// label 19 = zero row in wspb -> all 25 loads unconditional & independent.
__global__ void k_actv(const int* __restrict__ labels, const __bf16* __restrict__ wsp,
                       const float* __restrict__ ssb, __bf16* __restrict__ actv) {
  int b = blockIdx.x >> 6, h = blockIdx.x & 63;
  __shared__ int lab[5*68];
  for (int i = threadIdx.x; i < 5*68; i += 256) {
    int dh = i / 68, xx = i % 68;
    int hh = h + dh - 2, ww = xx - 2;
    int l = 19;
    if (hh >= 0 && hh < 64 && ww >= 0 && ww < 64) {
      int l0 = labels[b*4096 + hh*64 + ww];
      if (l0 >= 0) l = l0;
    }
    lab[i] = l;
  }
  __syncthreads();
  int t = threadIdx.x;                         // c-pair 2t, 2t+1
  float bs0 = ssb[2*t], bs1 = ssb[2*t + 1];
  for (int w = 0; w < 64; ++w) {
    float a0 = bs0, a1 = bs1;
    #pragma unroll
    for (int tap = 0; tap < 25; ++tap) {
      int l = lab[(tap/5)*68 + w + (tap%5)];   // wave-uniform
      bf16x2 v = *(const bf16x2*)(wsp + (size_t)(l*25 + tap)*512 + 2*t);
      a0 += (float)v[0]; a1 += (float)v[1];
    }
    size_t bse = (((size_t)b*68 + h + 2)*68 + (w + 2)) * 512;
    bf16x2 r; r[0] = (__bf16)fmaxf(a0, 0.f); r[1] = (__bf16)fmaxf(a1, 0.f);
    *(bf16x2*)(actv + bse + 2*t) = r;
  }
}

// ---- big implicit-GEMM conv (R1 structure, known 478us/41%): ---------------
// 128x128 tile, A+B staged 128x64 via global_load_lds w/ XOR chunk swizzle,
// 16x16x32 bf16 MFMA, NHWC epilogue.
__global__ __launch_bounds__(256) void k_conv(
    const __bf16* __restrict__ actv, const __bf16* __restrict__ wpk,
    const float* __restrict__ sgb, const float* __restrict__ sbb,
    __bf16* __restrict__ gbs) {
  __shared__ __align__(16) __bf16 ldsA[128*64];
  __shared__ __align__(16) __bf16 ldsB[128*64];
  const int tid = threadIdx.x;
  const int wv = tid >> 6, lane = tid & 63;
  const int m0 = blockIdx.x * 128, n0 = blockIdx.y * 128;
  const int b = m0 >> 12;

  int aoff[4], boff[4];
  #pragma unroll
  for (int i = 0; i < 4; ++i) {
    int p = (wv*4 + i)*64 + lane;     // 16B slot in tile
    int r = p >> 3, pc = p & 7;
    int cl = pc ^ (r & 7);            // logical chunk this lane fetches
    int pix = (m0 + r) & 4095;
    int h = pix >> 6, w = pix & 63;
    aoff[i] = ((b*68 + h)*68 + w)*512 + cl*8;
    boff[i] = (n0 + r)*512 + cl*8;
  }

  f32x4 acc[4][4] = {};
  const int wm = (wv >> 1) * 64, wn = (wv & 1) * 64;
  const int l15 = lane & 15, q = lane >> 4;

  for (int k5 = 0; k5 < 25; ++k5) {
    const int kh = k5 / 5, kw = k5 % 5;
    const int a_k = (kh*68 + kw)*512;
    const int b_k = k5 * 262144;
    for (int kc = 0; kc < 8; ++kc) {
      #pragma unroll
      for (int i = 0; i < 4; ++i) {
        gl_lds16(actv + aoff[i] + a_k + kc*64, ldsA + (wv*4 + i)*512);
        gl_lds16(wpk  + boff[i] + b_k + kc*64, ldsB + (wv*4 + i)*512);
      }
      __syncthreads();
      #pragma unroll
      for (int s = 0; s < 2; ++s) {
        bf16x8 af[4], bfr[4];
        #pragma unroll
        for (int mi = 0; mi < 4; ++mi) {
          int row = wm + mi*16 + l15;
          int ch = (s*4 + q) ^ (row & 7);
          af[mi] = *(const bf16x8*)(ldsA + row*64 + ch*8);
        }
        #pragma unroll
        for (int ni = 0; ni < 4; ++ni) {
          int row = wn + ni*16 + l15;
          int ch = (s*4 + q) ^ (row & 7);
          bfr[ni] = *(const bf16x8*)(ldsB + row*64 + ch*8);
        }
        #pragma unroll
        for (int mi = 0; mi < 4; ++mi)
          #pragma unroll
          for (int ni = 0; ni < 4; ++ni)
            acc[mi][ni] = __builtin_amdgcn_mfma_f32_16x16x32_bf16(
                af[mi], bfr[ni], acc[mi][ni], 0, 0, 0);
      }
      __syncthreads();
    }
  }

  // epilogue: D[row=q*4+r][col=l15]; NHWC store gbs[m][n] (+spade bias)
  #pragma unroll
  for (int ni = 0; ni < 4; ++ni) {
    int n = n0 + wn + ni*16 + l15;
    float bias = (n < 256) ? sgb[n] : sbb[n - 256];
    #pragma unroll
    for (int mi = 0; mi < 4; ++mi) {
      int m = m0 + wm + mi*16 + q*4;
      size_t base = (size_t)m*512 + n;
      #pragma unroll
      for (int r = 0; r < 4; ++r)
        gbs[base + (size_t)r*512] = (__bf16)(acc[mi][ni][r] + bias);
    }
  }
}

// ---- avg path: debranched 25-tap gather, 16 px/block, NHWC out -------------
// Aav row 3800 is all-zero -> unconditional loads.
__global__ void k_gather(const int* __restrict__ labels, const __bf16* __restrict__ A,
                         const float* __restrict__ cgb, const float* __restrict__ cbb,
                         __bf16* __restrict__ gba) {
  int wt = blockIdx.x & 3, h = (blockIdx.x >> 2) & 63, b = blockIdx.x >> 8;
  int w0 = wt * 16;
  __shared__ int rowbase[5*20];
  for (int i = threadIdx.x; i < 100; i += 256) {
    int dh = i / 20, xx = i % 20;
    int hh = h + dh - 2, ww = w0 + xx - 2;
    int l = (hh >= 0 && hh < 64 && ww >= 0 && ww < 64) ? labels[b*4096 + hh*64 + ww] : -1;
    rowbase[i] = (l >= 0) ? (b*19 + l)*25 : -1;    // add tap later; -1 -> zero row
  }
  __syncthreads();
  int t = threadIdx.x;                             // n-pair 2t, 2t+1
  float bs0, bs1;
  if (2*t < 256) { bs0 = cgb[2*t]; bs1 = cgb[2*t + 1]; }
  else           { bs0 = cbb[2*t - 256]; bs1 = cbb[2*t - 255]; }
  for (int px = 0; px < 16; ++px) {
    float a0 = bs0, a1 = bs1;
    #pragma unroll
    for (int tap = 0; tap < 25; ++tap) {
      int rb = rowbase[(tap/5)*20 + px + (tap%5)]; // wave-uniform
      int row = (rb >= 0) ? rb + tap : 3800;
      bf16x2 v = *(const bf16x2*)(A + (size_t)row*512 + 2*t);
      a0 += (float)v[0]; a1 += (float)v[1];
    }
    size_t o = ((size_t)b*4096 + h*64 + w0 + px) * 512;
    bf16x2 r; r[0] = (__bf16)a0; r[1] = (__bf16)a1;
    *(bf16x2*)(gba + o + 2*t) = r;
  }
}

// ---- final blend: NHWC->NCHW via LDS transpose -----------------------------
__global__ __launch_bounds__(256) void k_final(
    const float* __restrict__ x, const float* __restrict__ stats,
    const __bf16* __restrict__ gba, const __bf16* __restrict__ gbs,
    const float* __restrict__ blg, const float* __restrict__ blb,
    float* __restrict__ out) {
  __shared__ __bf16 tg_av[64*66], tb_av[64*66], tg_sp[64*66], tb_sp[64*66];
  int bidx = blockIdx.x;                   // 8b x 4ct x 64pt = 2048
  int pt = bidx & 63, ct = (bidx >> 6) & 3, b = bidx >> 8;
  int c0 = ct*64, p0 = pt*64;
  for (int i = threadIdx.x; i < 4096; i += 256) {
    int p = i >> 6, c = i & 63;
    size_t src = ((size_t)b*4096 + p0 + p)*512;
    int d = p*66 + c;
    tg_av[d] = gba[src + c0 + c];
    tb_av[d] = gba[src + 256 + c0 + c];
    tg_sp[d] = gbs[src + c0 + c];
    tb_sp[d] = gbs[src + 256 + c0 + c];
  }
  __syncthreads();
  float ga = 1.f / (1.f + expf(-blg[0]));
  float ba = 1.f / (1.f + expf(-blb[0]));
  int p = threadIdx.x & 63;
  for (int cl = threadIdx.x >> 6; cl < 64; cl += 4) {
    int c = c0 + cl;
    int bc = b*256 + c;
    float mean = stats[bc], rstd = stats[2048 + bc];
    size_t o = (size_t)bc*4096 + p0 + p;
    int d = p*66 + cl;
    float gf  = ga*(float)tg_av[d] + (1.f - ga)*(float)tg_sp[d];
    float bf_ = ba*(float)tb_av[d] + (1.f - ba)*(float)tb_sp[d];
    out[o] = (x[o] - mean)*rstd*(1.f + gf) + bf_;
  }
}

extern "C" void kernel_launch(void* const* d_in, const int* in_sizes, int n_in,
                              void* d_out, int out_size, void* d_ws, size_t ws_size,
                              hipStream_t stream) {
  const float* x    = (const float*)d_in[0];
  const float* seg  = (const float*)d_in[1];
  const float* sc   = (const float*)d_in[2];
  const float* fcw  = (const float*)d_in[3];
  const float* fcb  = (const float*)d_in[4];
  const float* cgw  = (const float*)d_in[5];
  const float* cgb  = (const float*)d_in[6];
  const float* cbw  = (const float*)d_in[7];
  const float* cbb  = (const float*)d_in[8];
  const float* ssw  = (const float*)d_in[9];
  const float* ssb  = (const float*)d_in[10];
  const float* sgw  = (const float*)d_in[11];
  const float* sgb  = (const float*)d_in[12];
  const float* sbw  = (const float*)d_in[13];
  const float* sbb  = (const float*)d_in[14];
  const float* blg  = (const float*)d_in[15];
  const float* blb  = (const float*)d_in[16];
  float* out = (float*)d_out;

  char* ws = (char*)d_ws;
  size_t off = 0;
  auto alloc = [&](size_t bytes) {
    void* p = ws + off; off += (bytes + 255) & ~(size_t)255; return p;
  };
  float*  stats = (float*)alloc(2048ull*2*4);
  int*    labels= (int*)  alloc(32768ull*4);
  float*  mu    = (float*)alloc(77824ull*4);
  __bf16* Aav   = (__bf16*)alloc((3800ull + 1)*512*2);  // + zero row 3800
  __bf16* wspb  = (__bf16*)alloc(20ull*25*512*2);       // j=19 zero rows
  float*  wpa   = (float*)alloc(25ull*512*512*4);       // 26.2 MB
  __bf16* wps   = (__bf16*)alloc(25ull*512*512*2);      // 13.1 MB
  __bf16* actv  = (__bf16*)alloc(8ull*68*68*512*2);     // 37.9 MB
  __bf16* gba   = (__bf16*)alloc(8ull*4096*512*2);      // 33.5 MB (NHWC)
  __bf16* gbs   = (__bf16*)alloc(8ull*4096*512*2);      // 33.5 MB (NHWC)

  hipMemsetAsync(actv, 0, 8ull*68*68*512*2, stream);    // zero pad border
  hipMemsetAsync(Aav + 3800ull*512, 0, 512*2, stream);  // zero gather row
  k_stats     <<<2048, 256, 0, stream>>>(x, stats);
  k_labels    <<<128, 256, 0, stream>>>(seg, labels);
  k_mu        <<<152, 512, 0, stream>>>(sc, fcw, fcb, mu);
  k_pack_avg  <<<1024, 256, 0, stream>>>(cgw, cbw, wpa);
  k_pack_spade<<<512, 256, 0, stream>>>(sgw, sbw, wps);
  k_pack_wsp  <<<1000, 256, 0, stream>>>(ssw, wspb);
  k_A_avg     <<<200, 512, 0, stream>>>(mu, wpa, Aav);
  k_actv      <<<512, 256, 0, stream>>>(labels, wspb, ssb, actv);
  k_conv      <<<dim3(256, 4), 256, 0, stream>>>(actv, wps, sgb, sbb, gbs);
  k_gather    <<<2048, 256, 0, stream>>>(labels, Aav, cgb, cbb, gba);
  k_final     <<<2048, 256, 0, stream>>>(x, stats, gba, gbs, blg, blb, out);
}

// Round 5
// 650.376 us; speedup vs baseline: 1.8034x; 1.3854x over previous
//
#include <hip/hip_runtime.h>
#include <hip/hip_bf16.h>
#include <stdint.h>

typedef __attribute__((__ext_vector_type__(8))) __bf16 bf16x8;
typedef __attribute__((__ext_vector_type__(2))) __bf16 bf16x2;
typedef __attribute__((__ext_vector_type__(4))) float  f32x4;
typedef __attribute__((__ext_vector_type__(8))) int    v8i;

// Fixed MX scales (e8m0): A quantized x2^8 -> scale byte 119 (2^-8),
// B quantized x2^6 -> scale byte 121 (2^-6). Byte replicated so any
// op_sel byte selection reads the same value.
#define SCALE_A_DW 0x77777777
#define SCALE_B_DW 0x79797979

// async 16B global->LDS (dest = wave-uniform base + lane*16)
__device__ __forceinline__ void gl_lds16(const void* g, void* l) {
  __builtin_amdgcn_global_load_lds(
      (__attribute__((address_space(1))) void*)(uintptr_t)g,
      (__attribute__((address_space(3))) void*)(unsigned)(uintptr_t)l,
      16, 0, 0);
}

// ---- fused prep: stats / labels / pack_avg / pack_wsp / Aav-zero-row -------
__global__ __launch_bounds__(256) void k_prep(
    const float* __restrict__ x, float* __restrict__ stats,
    const float* __restrict__ seg, int* __restrict__ labels,
    const float* __restrict__ cgw, const float* __restrict__ cbw,
    float* __restrict__ wpa,
    const float* __restrict__ ssw, __bf16* __restrict__ wspb,
    __bf16* __restrict__ Aav) {
  __shared__ __align__(16) char smem[16*401*4];
  int blk = blockIdx.x;
  if (blk < 2048) {                       // ---- instance-norm stats
    int bc = blk;
    const float4* p = (const float4*)(x + (size_t)bc * 4096);
    float s = 0.f, ss = 0.f;
    for (int i = threadIdx.x; i < 1024; i += 256) {
      float4 v = p[i];
      s  += v.x + v.y + v.z + v.w;
      ss += v.x*v.x + v.y*v.y + v.z*v.z + v.w*v.w;
    }
    #pragma unroll
    for (int o = 32; o > 0; o >>= 1) { s += __shfl_down(s, o); ss += __shfl_down(ss, o); }
    float* sh = (float*)smem;
    int wv = threadIdx.x >> 6;
    if ((threadIdx.x & 63) == 0) { sh[wv] = s; sh[4 + wv] = ss; }
    __syncthreads();
    if (threadIdx.x == 0) {
      float S = sh[0]+sh[1]+sh[2]+sh[3], SS = sh[4]+sh[5]+sh[6]+sh[7];
      float m = S * (1.f/4096.f);
      float var = SS * (1.f/4096.f) - m*m;
      stats[bc] = m;
      stats[2048 + bc] = rsqrtf(var + 1e-5f);
    }
  } else if (blk < 2176) {                // ---- labels (last one-hot j)
    int idx = (blk - 2048)*256 + threadIdx.x;       // 0..32767
    int b = idx >> 12, pix = idx & 4095;
    const float* p = seg + (size_t)b*19*4096 + pix;
    int lab = -1;
    for (int j = 0; j < 19; ++j) if (p[(size_t)j*4096] > 0.f) lab = j;
    labels[idx] = lab;
  } else if (blk < 3200) {                // ---- pack avg weights wpa[k5][c][n]
    int bid = blk - 2176;
    float* s = (float*)smem;
    int n0 = (bid & 31) * 16, c0 = (bid >> 5) * 16;
    for (int i = threadIdx.x; i < 6400; i += 256) {
      int nn = i / 400, qq = i % 400;
      int n = n0 + nn;
      const float* src = (n < 256) ? cgw + (size_t)n*12800 : cbw + (size_t)(n-256)*12800;
      s[nn*401 + qq] = src[c0*25 + qq];
    }
    __syncthreads();
    for (int i = threadIdx.x; i < 6400; i += 256) {
      int nn = i & 15, rest = i >> 4;
      int k5 = rest % 25, cc = rest / 25;
      wpa[((size_t)k5*512 + c0 + cc)*512 + n0 + nn] = s[nn*401 + cc*25 + k5];
    }
  } else if (blk < 4200) {                // ---- pack shared weights (j=19 zero)
    int idx = (blk - 3200)*256 + threadIdx.x;       // < 256000
    int o = idx & 511, k5 = (idx >> 9) % 25, j = idx / 12800;
    wspb[idx] = (j < 19) ? (__bf16)ssw[((size_t)o*19 + j)*25 + k5] : (__bf16)0.f;
  } else {                                // ---- Aav zero row 3800
    ((unsigned*)(Aav + 3800ull*512))[threadIdx.x] = 0;   // 256 dwords = 1024 B
  }
}

// ---------------- mu[b,j,e] = relu(sum_d sc[b,j,d]*fc_w[j,e,d] + fc_b) ------
__global__ __launch_bounds__(512) void k_mu(const float* __restrict__ sc,
                                            const float* __restrict__ fcw,
                                            const float* __restrict__ fcb,
                                            float* __restrict__ mu) {
  int b = blockIdx.x / 19, j = blockIdx.x % 19;
  __shared__ float s[512];
  s[threadIdx.x] = sc[(b*19 + j)*512 + threadIdx.x];
  __syncthreads();
  int e = threadIdx.x;
  const float4* w4 = (const float4*)(fcw + ((size_t)(j*512 + e))*512);
  const float4* s4 = (const float4*)s;
  float acc = 0.f;
  for (int d = 0; d < 128; ++d) {
    float4 w = w4[d], v = s4[d];
    acc += w.x*v.x + w.y*v.y + w.z*v.z + w.w*v.w;
  }
  acc += fcb[j*512 + e];
  mu[(b*19 + j)*512 + e] = fmaxf(acc, 0.f);
}

// ---- pack spade weights -> fp8 e4m3, fixed scale x2^6: wq[k5][n][c] --------
__global__ __launch_bounds__(256) void k_pack_spade(
    const float* __restrict__ g, const float* __restrict__ bt,
    uint8_t* __restrict__ wq) {
  int n = blockIdx.x;                               // 0..511
  const float* src = (n < 256) ? g + (size_t)n*12800 : bt + (size_t)(n-256)*12800;
  __shared__ float s[12800];
  for (int i = threadIdx.x; i < 12800; i += 256) s[i] = src[i];
  __syncthreads();
  int t = threadIdx.x;
  for (int k5 = 0; k5 < 25; ++k5) {
    float w0 = s[(2*t)*25 + k5] * 64.f, w1 = s[(2*t+1)*25 + k5] * 64.f;
    int pk = __builtin_amdgcn_cvt_pk_fp8_f32(w0, w1, 0, false);
    *(unsigned short*)(wq + ((size_t)k5*512 + n)*512 + 2*t) = (unsigned short)pk;
  }
}

// ---- A[b,j,k5,n] = sum_c mu[b,j,c]*wpa[k5][c][n]  (mu via scalar loads) ----
__global__ __launch_bounds__(512) void k_A_avg(const float* __restrict__ mu,
                                               const float* __restrict__ wpa,
                                               __bf16* __restrict__ A) {
  int b = blockIdx.x / 25, k5 = blockIdx.x % 25;
  int n = threadIdx.x;
  const float* wp = wpa + (size_t)k5*262144 + n;
  const float* mub = mu + b*19*512;                 // wave-uniform rows -> s_load
  float acc[19];
  #pragma unroll
  for (int j = 0; j < 19; ++j) acc[j] = 0.f;
  for (int c = 0; c < 512; ++c) {
    float w = wp[(size_t)c*512];
    #pragma unroll
    for (int j = 0; j < 19; ++j) acc[j] += mub[j*512 + c] * w;
  }
  #pragma unroll
  for (int j = 0; j < 19; ++j)
    A[((size_t)((b*19 + j)*25 + k5))*512 + n] = (__bf16)acc[j];
}

// ---- actv: debranched gather -> fp8 e4m3 (x2^8) NHWC padded ----------------
// Writes its own zero borders (rows hp<2, hp>=66 and cols wp in {0,1,66,67}).
__global__ void k_actv(const int* __restrict__ labels, const __bf16* __restrict__ wsp,
                       const float* __restrict__ ssb, uint8_t* __restrict__ actv) {
  int b = blockIdx.x / 68, hp = blockIdx.x % 68;
  int t = threadIdx.x;
  size_t rowbase = ((size_t)b*68 + hp)*68;          // padded pixel index base
  if (hp < 2 || hp >= 66) {                         // full zero row
    unsigned* dp = (unsigned*)(actv + rowbase*512);
    for (int i = t; i < 8704; i += 256) dp[i] = 0;
    return;
  }
  int h = hp - 2;
  __shared__ int lab[5*68];
  for (int i = t; i < 5*68; i += 256) {
    int dh = i / 68, xx = i % 68;
    int hh = h + dh - 2, ww = xx - 2;
    int l = 19;
    if (hh >= 0 && hh < 64 && ww >= 0 && ww < 64) {
      int l0 = labels[b*4096 + hh*64 + ww];
      if (l0 >= 0) l = l0;
    }
    lab[i] = l;
  }
  {                                                 // left/right border pixels
    unsigned* dp = (unsigned*)(actv + rowbase*512);
    dp[t] = 0; dp[66*128 + t] = 0;                  // pixels 0,1 and 66,67
  }
  __syncthreads();
  float bs0 = ssb[2*t], bs1 = ssb[2*t + 1];
  for (int w = 0; w < 64; ++w) {
    float a0 = bs0, a1 = bs1;
    #pragma unroll
    for (int tap = 0; tap < 25; ++tap) {
      int l = lab[(tap/5)*68 + w + (tap%5)];        // wave-uniform
      bf16x2 v = *(const bf16x2*)(wsp + (size_t)(l*25 + tap)*512 + 2*t);
      a0 += (float)v[0]; a1 += (float)v[1];
    }
    a0 = fmaxf(a0, 0.f) * 256.f;
    a1 = fmaxf(a1, 0.f) * 256.f;
    int pk = __builtin_amdgcn_cvt_pk_fp8_f32(a0, a1, 0, false);
    *(unsigned short*)(actv + (rowbase + 2 + w)*512 + 2*t) = (unsigned short)pk;
  }
}

// ---- implicit-GEMM conv, MXFP8 fixed-scale: M=32768, N=512, K=12800 --------
// R3 structure (128x128 tile, XOR-swizzled global_load_lds staging) with
// mfma_scale_f32_16x16x128_f8f6f4 and compile-time uniform e8m0 scales:
// any lane->k permutation cancels identically between A and B.
__global__ __launch_bounds__(256) void k_conv(
    const uint8_t* __restrict__ actv, const uint8_t* __restrict__ wq,
    const float* __restrict__ sgb, const float* __restrict__ sbb,
    __bf16* __restrict__ gbs) {
  __shared__ __align__(16) uint8_t ldsA[16384];     // 128 rows x 128 B
  __shared__ __align__(16) uint8_t ldsB[16384];
  const int tid = threadIdx.x, wv = tid >> 6, lane = tid & 63;
  const int l15 = lane & 15, q = lane >> 4;
  const int m0 = blockIdx.x * 128, n0 = blockIdx.y * 128;
  const int b = m0 >> 12;

  int aoff[4], boff[4];                             // staging offsets (bytes)
  #pragma unroll
  for (int i = 0; i < 4; ++i) {
    int p = (wv*4 + i)*64 + lane;                   // 16B slot
    int r = p >> 3, pc = p & 7;
    int cl = pc ^ (r & 7);                          // logical chunk fetched
    int pix = (m0 + r) & 4095;
    int h = pix >> 6, w = pix & 63;
    aoff[i] = ((b*68 + h)*68 + w)*512 + cl*16;
    boff[i] = (n0 + r)*512 + cl*16;
  }

  const int wm = (wv >> 1) * 64, wn = (wv & 1) * 64;
  f32x4 acc[4][4] = {};

  for (int k5 = 0; k5 < 25; ++k5) {
    const int kh = k5/5, kw = k5%5;
    const int a_k = (kh*68 + kw)*512;
    const size_t b_k = (size_t)k5*262144;

    #pragma unroll
    for (int kc = 0; kc < 4; ++kc) {
      #pragma unroll
      for (int i = 0; i < 4; ++i) {
        gl_lds16(actv + aoff[i] + a_k + kc*128, ldsA + (wv*4 + i)*1024);
        gl_lds16(wq   + boff[i] + b_k + kc*128, ldsB + (wv*4 + i)*1024);
      }
      __syncthreads();
      v8i bfr[4];
      #pragma unroll
      for (int ni = 0; ni < 4; ++ni) {
        int row = wn + ni*16 + l15;
        const uint8_t* base = ldsB + row*128;
        union { v8i v; uint4 u[2]; } tt;
        tt.u[0] = *(const uint4*)(base + ((2*q    ) ^ (row & 7))*16);
        tt.u[1] = *(const uint4*)(base + ((2*q + 1) ^ (row & 7))*16);
        bfr[ni] = tt.v;
      }
      #pragma unroll
      for (int mi = 0; mi < 4; ++mi) {
        int row = wm + mi*16 + l15;
        const uint8_t* base = ldsA + row*128;
        union { v8i v; uint4 u[2]; } tt;
        tt.u[0] = *(const uint4*)(base + ((2*q    ) ^ (row & 7))*16);
        tt.u[1] = *(const uint4*)(base + ((2*q + 1) ^ (row & 7))*16);
        v8i af = tt.v;
        #pragma unroll
        for (int ni = 0; ni < 4; ++ni)
          acc[mi][ni] = __builtin_amdgcn_mfma_scale_f32_16x16x128_f8f6f4(
              af, bfr[ni], acc[mi][ni], 0, 0, 0, SCALE_A_DW, 0, SCALE_B_DW);
      }
      __syncthreads();
    }
  }

  // epilogue: D[row=q*4+r][col=l15]; NHWC store gbs[m][n] (+spade bias)
  #pragma unroll
  for (int ni = 0; ni < 4; ++ni) {
    int n = n0 + wn + ni*16 + l15;
    float bias = (n < 256) ? sgb[n] : sbb[n - 256];
    #pragma unroll
    for (int mi = 0; mi < 4; ++mi) {
      int m = m0 + wm + mi*16 + q*4;
      size_t base = (size_t)m*512 + n;
      #pragma unroll
      for (int r = 0; r < 4; ++r)
        gbs[base + (size_t)r*512] = (__bf16)(acc[mi][ni][r] + bias);
    }
  }
}

// ---- avg path: debranched 25-tap gather, 16 px/block, NHWC out -------------
__global__ void k_gather(const int* __restrict__ labels, const __bf16* __restrict__ A,
                         const float* __restrict__ cgb, const float* __restrict__ cbb,
                         __bf16* __restrict__ gba) {
  int wt = blockIdx.x & 3, h = (blockIdx.x >> 2) & 63, b = blockIdx.x >> 8;
  int w0 = wt * 16;
  __shared__ int rowbase[5*20];
  for (int i = threadIdx.x; i < 100; i += 256) {
    int dh = i / 20, xx = i % 20;
    int hh = h + dh - 2, ww = w0 + xx - 2;
    int l = (hh >= 0 && hh < 64 && ww >= 0 && ww < 64) ? labels[b*4096 + hh*64 + ww] : -1;
    rowbase[i] = (l >= 0) ? (b*19 + l)*25 : -1;
  }
  __syncthreads();
  int t = threadIdx.x;
  float bs0, bs1;
  if (2*t < 256) { bs0 = cgb[2*t]; bs1 = cgb[2*t + 1]; }
  else           { bs0 = cbb[2*t - 256]; bs1 = cbb[2*t - 255]; }
  for (int px = 0; px < 16; ++px) {
    float a0 = bs0, a1 = bs1;
    #pragma unroll
    for (int tap = 0; tap < 25; ++tap) {
      int rb = rowbase[(tap/5)*20 + px + (tap%5)];
      int row = (rb >= 0) ? rb + tap : 3800;
      bf16x2 v = *(const bf16x2*)(A + (size_t)row*512 + 2*t);
      a0 += (float)v[0]; a1 += (float)v[1];
    }
    size_t o = ((size_t)b*4096 + h*64 + w0 + px) * 512;
    bf16x2 r; r[0] = (__bf16)a0; r[1] = (__bf16)a1;
    *(bf16x2*)(gba + o + 2*t) = r;
  }
}

// ---- final blend: NHWC->NCHW via LDS transpose -----------------------------
__global__ __launch_bounds__(256) void k_final(
    const float* __restrict__ x, const float* __restrict__ stats,
    const __bf16* __restrict__ gba, const __bf16* __restrict__ gbs,
    const float* __restrict__ blg, const float* __restrict__ blb,
    float* __restrict__ out) {
  __shared__ __bf16 tg_av[64*66], tb_av[64*66], tg_sp[64*66], tb_sp[64*66];
  int bidx = blockIdx.x;                   // 8b x 4ct x 64pt
  int pt = bidx & 63, ct = (bidx >> 6) & 3, b = bidx >> 8;
  int c0 = ct*64, p0 = pt*64;
  for (int i = threadIdx.x; i < 4096; i += 256) {
    int p = i >> 6, c = i & 63;
    size_t src = ((size_t)b*4096 + p0 + p)*512;
    int d = p*66 + c;
    tg_av[d] = gba[src + c0 + c];
    tb_av[d] = gba[src + 256 + c0 + c];
    tg_sp[d] = gbs[src + c0 + c];
    tb_sp[d] = gbs[src + 256 + c0 + c];
  }
  __syncthreads();
  float ga = 1.f / (1.f + expf(-blg[0]));
  float ba = 1.f / (1.f + expf(-blb[0]));
  int p = threadIdx.x & 63;
  for (int cl = threadIdx.x >> 6; cl < 64; cl += 4) {
    int c = c0 + cl;
    int bc = b*256 + c;
    float mean = stats[bc], rstd = stats[2048 + bc];
    size_t o = (size_t)bc*4096 + p0 + p;
    int d = p*66 + cl;
    float gf  = ga*(float)tg_av[d] + (1.f - ga)*(float)tg_sp[d];
    float bf_ = ba*(float)tb_av[d] + (1.f - ba)*(float)tb_sp[d];
    out[o] = (x[o] - mean)*rstd*(1.f + gf) + bf_;
  }
}

extern "C" void kernel_launch(void* const* d_in, const int* in_sizes, int n_in,
                              void* d_out, int out_size, void* d_ws, size_t ws_size,
                              hipStream_t stream) {
  const float* x    = (const float*)d_in[0];
  const float* seg  = (const float*)d_in[1];
  const float* sc   = (const float*)d_in[2];
  const float* fcw  = (const float*)d_in[3];
  const float* fcb  = (const float*)d_in[4];
  const float* cgw  = (const float*)d_in[5];
  const float* cgb  = (const float*)d_in[6];
  const float* cbw  = (const float*)d_in[7];
  const float* cbb  = (const float*)d_in[8];
  const float* ssw  = (const float*)d_in[9];
  const float* ssb  = (const float*)d_in[10];
  const float* sgw  = (const float*)d_in[11];
  const float* sgb  = (const float*)d_in[12];
  const float* sbw  = (const float*)d_in[13];
  const float* sbb  = (const float*)d_in[14];
  const float* blg  = (const float*)d_in[15];
  const float* blb  = (const float*)d_in[16];
  float* out = (float*)d_out;

  char* ws = (char*)d_ws;
  size_t off = 0;
  auto alloc = [&](size_t bytes) {
    void* p = ws + off; off += (bytes + 255) & ~(size_t)255; return p;
  };
  float*   stats = (float*)alloc(2048ull*2*4);
  int*     labels= (int*)  alloc(32768ull*4);
  float*   mu    = (float*)alloc(77824ull*4);
  __bf16*  Aav   = (__bf16*)alloc((3800ull + 1)*512*2);  // + zero row 3800
  __bf16*  wspb  = (__bf16*)alloc(20ull*25*512*2);       // j=19 zero rows
  float*   wpa   = (float*)alloc(25ull*512*512*4);       // 26.2 MB
  uint8_t* wq    = (uint8_t*)alloc(25ull*512*512);       // 6.6 MB fp8
  uint8_t* actv  = (uint8_t*)alloc(8ull*68*68*512);      // 18.9 MB fp8 NHWC pad
  __bf16*  gba   = (__bf16*)alloc(8ull*4096*512*2);      // 33.5 MB (NHWC)
  __bf16*  gbs   = (__bf16*)alloc(8ull*4096*512*2);      // 33.5 MB (NHWC)

  k_prep      <<<4201, 256, 0, stream>>>(x, stats, seg, labels, cgw, cbw, wpa, ssw, wspb, Aav);
  k_mu        <<<152, 512, 0, stream>>>(sc, fcw, fcb, mu);
  k_pack_spade<<<512, 256, 0, stream>>>(sgw, sbw, wq);
  k_A_avg     <<<200, 512, 0, stream>>>(mu, wpa, Aav);
  k_actv      <<<544, 256, 0, stream>>>(labels, wspb, ssb, actv);
  k_conv      <<<dim3(256, 4), 256, 0, stream>>>(actv, wq, sgb, sbb, gbs);
  k_gather    <<<2048, 256, 0, stream>>>(labels, Aav, cgb, cbb, gba);
  k_final     <<<2048, 256, 0, stream>>>(x, stats, gba, gbs, blg, blb, out);
}